// Round 2
// baseline (1067.651 us; speedup 1.0000x reference)
//
#include <hip/hip_runtime.h>

// ---------------- types / helpers ----------------
typedef float f32x4 __attribute__((ext_vector_type(4)));
typedef __bf16 bf16x8 __attribute__((ext_vector_type(8)));
typedef unsigned short ushortx8 __attribute__((ext_vector_type(8)));

__device__ __forceinline__ unsigned short f2bf(float f) {
  unsigned int u = __builtin_bit_cast(unsigned int, f);
  u += 0x7fffu + ((u >> 16) & 1u);
  return (unsigned short)(u >> 16);
}
__device__ __forceinline__ float bf2f(unsigned short s) {
  return __builtin_bit_cast(float, ((unsigned int)s) << 16);
}

#define GLDS16(gp, lp)                                                         \
  __builtin_amdgcn_global_load_lds(                                            \
      (const __attribute__((address_space(1))) unsigned int*)(const void*)(gp),\
      (__attribute__((address_space(3))) unsigned int*)(void*)(lp), 16, 0, 0)

// ---------------- fp32 -> bf16 convert ----------------
__global__ void cvt_kernel(const float* __restrict__ in,
                           unsigned short* __restrict__ out) {
  int i = (blockIdx.x * 256 + threadIdx.x) * 4;  // grid sized exactly
  float4 v = *reinterpret_cast<const float4*>(in + i);
  ushort4 o;
  o.x = f2bf(v.x); o.y = f2bf(v.y); o.z = f2bf(v.z); o.w = f2bf(v.w);
  *reinterpret_cast<ushort4*>(out + i) = o;
}

// ---------------- bf16 GEMM: C[M][N] = A[M][K] * B[N][K]^T ----------------
// 128x128 tile, BK=32, 4 waves (2x2), each wave 64x64 via 4x4 16x16x32 MFMA.
// Staging via global_load_lds width-16, linear LDS (m97 structure).
template <typename OutT>
__global__ __launch_bounds__(256, 2) void gemm_bt(
    const unsigned short* __restrict__ Ap, const unsigned short* __restrict__ Bp,
    OutT* __restrict__ Cp, int M, int N, int K) {
  __shared__ __align__(16) unsigned short smem[2 * 128 * 32];
  const int tid = threadIdx.x;
  const int wave = tid >> 6, lane = tid & 63;
  const int g = lane >> 4, l15 = lane & 15;
  const int bm = blockIdx.x * 128, bn = blockIdx.y * 128;
  const int wm = (wave >> 1) * 64, wn = (wave & 1) * 64;
  unsigned short* As = smem;
  unsigned short* Bs = smem + 128 * 32;
  f32x4 acc[4][4] = {};
  for (int k0 = 0; k0 < K; k0 += 32) {
    __syncthreads();  // previous tile reads done
    // stage A (units 0..511) + B (units 512..1023); 16B units, linear LDS
#pragma unroll
    for (int j = 0; j < 4; ++j) {
      int unit = wave * 256 + j * 64 + lane;
      const unsigned short* gp;
      if (unit < 512) {
        gp = Ap + (size_t)(bm + (unit >> 2)) * K + k0 + (unit & 3) * 8;
      } else {
        int bu = unit - 512;
        gp = Bp + (size_t)(bn + (bu >> 2)) * K + k0 + (bu & 3) * 8;
      }
      GLDS16(gp, (char*)smem + (wave * 256 + j * 64) * 16);
    }
    __syncthreads();  // staging visible (drains vmcnt)
    bf16x8 a[4], b[4];
#pragma unroll
    for (int mi = 0; mi < 4; ++mi)
      a[mi] = *reinterpret_cast<const bf16x8*>(&As[(wm + mi * 16 + l15) * 32 + g * 8]);
#pragma unroll
    for (int nj = 0; nj < 4; ++nj)
      b[nj] = *reinterpret_cast<const bf16x8*>(&Bs[(wn + nj * 16 + l15) * 32 + g * 8]);
#pragma unroll
    for (int mi = 0; mi < 4; ++mi)
#pragma unroll
      for (int nj = 0; nj < 4; ++nj)
        acc[mi][nj] = __builtin_amdgcn_mfma_f32_16x16x32_bf16(a[mi], b[nj], acc[mi][nj], 0, 0, 0);
  }
  // epilogue: C/D layout col=lane&15, row=g*4+reg
#pragma unroll
  for (int mi = 0; mi < 4; ++mi)
#pragma unroll
    for (int nj = 0; nj < 4; ++nj) {
      int r0 = bm + wm + mi * 16 + g * 4;
      int c0 = bn + wn + nj * 16 + l15;
#pragma unroll
      for (int r = 0; r < 4; ++r) {
        float v = acc[mi][nj][r];
        if constexpr (sizeof(OutT) == 2)
          Cp[(size_t)(r0 + r) * N + c0] = (OutT)f2bf(v);
        else
          Cp[(size_t)(r0 + r) * N + c0] = (OutT)v;
      }
    }
}

// ---------------- RoPE + repack (q scaled by 1/sqrt(d)) ----------------
// q_ws[b*S+s][32*128] -> q_r[b][32][s][128] ; k_ws -> k_r[b][8][s][128]
__global__ void rope_repack(const unsigned short* __restrict__ qws,
                            const unsigned short* __restrict__ kws,
                            const float* __restrict__ cosT,
                            const float* __restrict__ sinT,
                            unsigned short* __restrict__ qr,
                            unsigned short* __restrict__ kr) {
  const int row = blockIdx.x;           // b*S + s
  const int b = row >> 11, s = row & 2047;
  const int t = threadIdx.x;
  const int h = t >> 3, d0 = (t & 7) * 8;
  const float* cr = cosT + s * 128;
  const float* sr = sinT + s * 128;
  float cl[8], chh[8], sl[8], shh[8];
#pragma unroll
  for (int i = 0; i < 8; ++i) {
    cl[i] = cr[d0 + i]; chh[i] = cr[64 + d0 + i];
    sl[i] = sr[d0 + i]; shh[i] = sr[64 + d0 + i];
  }
  constexpr float SCALE = 0.08838834764831845f;  // 1/sqrt(128)
  {
    const unsigned short* px = &qws[(size_t)row * 4096 + h * 128 + d0];
    ushortx8 xl = *reinterpret_cast<const ushortx8*>(px);
    ushortx8 xh = *reinterpret_cast<const ushortx8*>(px + 64);
    ushortx8 ol, oh;
#pragma unroll
    for (int i = 0; i < 8; ++i) {
      float lo = bf2f(xl[i]), hi = bf2f(xh[i]);
      ol[i] = f2bf((lo * cl[i] - hi * sl[i]) * SCALE);
      oh[i] = f2bf((hi * chh[i] + lo * shh[i]) * SCALE);
    }
    unsigned short* po = &qr[((size_t)(b * 32 + h) * 2048 + s) * 128 + d0];
    *reinterpret_cast<ushortx8*>(po) = ol;
    *reinterpret_cast<ushortx8*>(po + 64) = oh;
  }
  if (t < 64) {  // h in 0..7 for K
    const unsigned short* px = &kws[(size_t)row * 1024 + h * 128 + d0];
    ushortx8 xl = *reinterpret_cast<const ushortx8*>(px);
    ushortx8 xh = *reinterpret_cast<const ushortx8*>(px + 64);
    ushortx8 ol, oh;
#pragma unroll
    for (int i = 0; i < 8; ++i) {
      float lo = bf2f(xl[i]), hi = bf2f(xh[i]);
      ol[i] = f2bf(lo * cl[i] - hi * sl[i]);
      oh[i] = f2bf(hi * chh[i] + lo * shh[i]);
    }
    unsigned short* po = &kr[((size_t)(b * 8 + h) * 2048 + s) * 128 + d0];
    *reinterpret_cast<ushortx8*>(po) = ol;
    *reinterpret_cast<ushortx8*>(po + 64) = oh;
  }
}

// ---------------- V transpose: v_ws[b*S+s][8*128] -> v_t[b][8][128][S] -----
__global__ void transpose_v(const unsigned short* __restrict__ vws,
                            unsigned short* __restrict__ vt) {
  const int blk = blockIdx.x;
  const int s0 = (blk & 31) * 64;
  const int bh = blk >> 5;  // b*8+h
  const int b = bh >> 3, h = bh & 7;
  const int t = threadIdx.x;
  __shared__ __align__(16) unsigned short tile[64][136];
  // load full 64 s-rows x 128 d-cols tile: 1024 units of 8 shorts
#pragma unroll
  for (int p = 0; p < 4; ++p) {
    int u = p * 256 + t;
    int r = u >> 4, c = (u & 15) * 8;
    ushortx8 v = *reinterpret_cast<const ushortx8*>(
        &vws[(size_t)(b * 2048 + s0 + r) * 1024 + h * 128 + c]);
    *reinterpret_cast<ushortx8*>(&tile[r][c]) = v;
  }
  __syncthreads();
#pragma unroll
  for (int p = 0; p < 4; ++p) {
    int u = p * 256 + t;
    int d = u >> 3, sseg = (u & 7) * 8;
    ushortx8 w;
#pragma unroll
    for (int i = 0; i < 8; ++i) w[i] = tile[sseg + i][d];
    *reinterpret_cast<ushortx8*>(&vt[((size_t)bh * 128 + d) * 2048 + s0 + sseg]) = w;
  }
}

// ---------------- flash attention (causal, GQA 4:1) ----------------
// grid (S/64, B*32). 4 waves, each wave 16 q-rows. KV tiles of 64.
__global__ __launch_bounds__(256, 2) void attn_kernel(
    const unsigned short* __restrict__ qr, const unsigned short* __restrict__ kr,
    const unsigned short* __restrict__ vt, unsigned short* __restrict__ attn) {
  const int qblk = blockIdx.x;
  const int bh = blockIdx.y;
  const int b = bh >> 5, h = bh & 31, hkv = h >> 2;
  const int tid = threadIdx.x, wave = tid >> 6, lane = tid & 63;
  const int g = lane >> 4, l15 = lane & 15;
  const int qs = qblk * 64;
  __shared__ __align__(16) unsigned short Ks[64 * 128];   // swizzled [kv][d]
  __shared__ __align__(16) unsigned short Vs[128 * 64];   // swizzled [d][kv]
  __shared__ __align__(16) unsigned short Pl[4][16 * 72]; // per-wave P, pad 72
  const unsigned short* qbase = qr + (size_t)(b * 32 + h) * 2048 * 128;
  const unsigned short* kbase = kr + (size_t)(b * 8 + hkv) * 2048 * 128;
  const unsigned short* vbase = vt + (size_t)(b * 8 + hkv) * 128 * 2048;
  // Q fragments held in registers for the whole kernel
  bf16x8 qf[4];
  const int qrow = qs + wave * 16 + l15;
#pragma unroll
  for (int c = 0; c < 4; ++c)
    qf[c] = *reinterpret_cast<const bf16x8*>(&qbase[(size_t)qrow * 128 + c * 32 + g * 8]);
  f32x4 o[8] = {};
  float m_[4], l_[4];
#pragma unroll
  for (int r = 0; r < 4; ++r) { m_[r] = -1e30f; l_[r] = 0.f; }

  for (int tkv = 0; tkv <= qblk; ++tkv) {
    const int kv0 = tkv * 64;
    __syncthreads();  // previous tile's reads complete
    // stage K tile [64][128] (1024 x 16B units), XOR swizzle (row&7)<<4
#pragma unroll
    for (int p = 0; p < 4; ++p) {
      int u = p * 256 + tid;
      int r = u >> 4, cby = (u & 15) * 16;
      ushortx8 kvv = *reinterpret_cast<const ushortx8*>(
          &kbase[(size_t)(kv0 + r) * 128 + cby / 2]);
      *reinterpret_cast<ushortx8*>((char*)Ks + ((r * 256 + cby) ^ ((r & 7) << 4))) = kvv;
    }
    // stage V^T tile [128][64]
#pragma unroll
    for (int p = 0; p < 4; ++p) {
      int u = p * 256 + tid;
      int r = u >> 3, cby = (u & 7) * 16;
      ushortx8 vvv = *reinterpret_cast<const ushortx8*>(
          &vbase[(size_t)r * 2048 + kv0 + cby / 2]);
      *reinterpret_cast<ushortx8*>((char*)Vs + ((r * 128 + cby) ^ ((r & 7) << 4))) = vvv;
    }
    __syncthreads();
    // S = Q K^T  (scale folded into Q)
    f32x4 sc[4];
#pragma unroll
    for (int nb = 0; nb < 4; ++nb) {
      f32x4 a4 = {0.f, 0.f, 0.f, 0.f};
      const int n = nb * 16 + l15;
#pragma unroll
      for (int c = 0; c < 4; ++c) {
        int kby = (c * 32 + g * 8) * 2;
        bf16x8 kf = *reinterpret_cast<const bf16x8*>(
            (char*)Ks + ((n * 256 + kby) ^ ((n & 7) << 4)));
        a4 = __builtin_amdgcn_mfma_f32_16x16x32_bf16(qf[c], kf, a4, 0, 0, 0);
      }
      sc[nb] = a4;
    }
    // causal mask on diagonal tile
    if (tkv == qblk) {
#pragma unroll
      for (int nb = 0; nb < 4; ++nb) {
        int kv = kv0 + nb * 16 + l15;
#pragma unroll
        for (int r = 0; r < 4; ++r)
          if (kv > qs + wave * 16 + g * 4 + r) sc[nb][r] = -1e30f;
      }
    }
    // online softmax: row stats via 16-lane shuffles
    float sf[4];
#pragma unroll
    for (int r = 0; r < 4; ++r) {
      float tm = fmaxf(fmaxf(sc[0][r], sc[1][r]), fmaxf(sc[2][r], sc[3][r]));
#pragma unroll
      for (int off = 8; off; off >>= 1) tm = fmaxf(tm, __shfl_xor(tm, off, 16));
      float mn = fmaxf(m_[r], tm);
      sf[r] = __expf(m_[r] - mn);
      m_[r] = mn;
    }
    float rs[4] = {0.f, 0.f, 0.f, 0.f};
#pragma unroll
    for (int nb = 0; nb < 4; ++nb)
#pragma unroll
      for (int r = 0; r < 4; ++r) {
        float p = __expf(sc[nb][r] - m_[r]);
        sc[nb][r] = p;
        rs[r] += p;
      }
#pragma unroll
    for (int r = 0; r < 4; ++r) {
#pragma unroll
      for (int off = 8; off; off >>= 1) rs[r] += __shfl_xor(rs[r], off, 16);
      l_[r] = l_[r] * sf[r] + rs[r];
    }
#pragma unroll
    for (int db = 0; db < 8; ++db)
#pragma unroll
      for (int r = 0; r < 4; ++r) o[db][r] *= sf[r];
    // P -> LDS (re-layout for PV A-operand), wave-local
    unsigned short* pw = &Pl[wave][0];
#pragma unroll
    for (int nb = 0; nb < 4; ++nb)
#pragma unroll
      for (int r = 0; r < 4; ++r)
        pw[(g * 4 + r) * 72 + nb * 16 + l15] = f2bf(sc[nb][r]);
    asm volatile("s_waitcnt lgkmcnt(0)" ::: "memory");
    __builtin_amdgcn_sched_barrier(0);
    // O += P V
#pragma unroll
    for (int c2 = 0; c2 < 2; ++c2) {
      bf16x8 pf = *reinterpret_cast<const bf16x8*>(&pw[l15 * 72 + c2 * 32 + g * 8]);
#pragma unroll
      for (int db = 0; db < 8; ++db) {
        int n = db * 16 + l15;
        int kby = (c2 * 32 + g * 8) * 2;
        bf16x8 vf = *reinterpret_cast<const bf16x8*>(
            (char*)Vs + ((n * 128 + kby) ^ ((n & 7) << 4)));
        o[db] = __builtin_amdgcn_mfma_f32_16x16x32_bf16(pf, vf, o[db], 0, 0, 0);
      }
    }
  }
  // epilogue: normalize, stage to LDS (reuse Ks), coalesced store
  float inv[4];
#pragma unroll
  for (int r = 0; r < 4; ++r) inv[r] = 1.f / l_[r];
  __syncthreads();  // all waves done reading Ks/Vs
  unsigned short* ob = &Ks[wave * 2048];
#pragma unroll
  for (int db = 0; db < 8; ++db)
#pragma unroll
    for (int r = 0; r < 4; ++r)
      ob[(g * 4 + r) * 128 + db * 16 + l15] = f2bf(o[db][r] * inv[r]);
  asm volatile("s_waitcnt lgkmcnt(0)" ::: "memory");
  __builtin_amdgcn_sched_barrier(0);
#pragma unroll
  for (int p = 0; p < 4; ++p) {
    int u = p * 64 + lane;
    int rr = u >> 4, seg = (u & 15) * 8;
    ushortx8 w = *reinterpret_cast<const ushortx8*>(&ob[rr * 128 + seg]);
    *reinterpret_cast<ushortx8*>(
        &attn[(size_t)(b * 2048 + qs + wave * 16 + rr) * 4096 + h * 128 + seg]) = w;
  }
}

// ---------------- host ----------------
extern "C" void kernel_launch(void* const* d_in, const int* in_sizes, int n_in,
                              void* d_out, int out_size, void* d_ws, size_t ws_size,
                              hipStream_t stream) {
  const float* hs   = (const float*)d_in[0];
  const float* Wq   = (const float*)d_in[1];
  const float* Wk   = (const float*)d_in[2];
  const float* Wv   = (const float*)d_in[3];
  const float* Wo   = (const float*)d_in[4];
  const float* cosT = (const float*)d_in[5];
  const float* sinT = (const float*)d_in[6];
  char* ws = (char*)d_ws;
  // workspace layout (bytes); dead buffers are aliased later in the pipeline
  unsigned short* hs_bf = (unsigned short*)(ws + 0);          // 33.5MB, later attn buffer
  unsigned short* wq_bf = (unsigned short*)(ws + 33554432);   // 33.5MB, later q_r
  unsigned short* wk_bf = (unsigned short*)(ws + 67108864);   // 8.4MB,  later k_r
  unsigned short* wv_bf = (unsigned short*)(ws + 75497472);   // 8.4MB,  later v_t
  unsigned short* wo_bf = (unsigned short*)(ws + 83886080);   // 33.5MB
  unsigned short* q_ws  = (unsigned short*)(ws + 117440512);  // 33.5MB
  unsigned short* k_ws  = (unsigned short*)(ws + 150994944);  // 8.4MB
  unsigned short* v_ws  = (unsigned short*)(ws + 159383552);  // 8.4MB -> total 160MB
  unsigned short* q_r   = wq_bf;
  unsigned short* k_r   = wk_bf;
  unsigned short* v_t   = wv_bf;
  unsigned short* attnb = hs_bf;
  float* out = (float*)d_out;

  cvt_kernel<<<16384, 256, 0, stream>>>(hs, hs_bf);
  cvt_kernel<<<16384, 256, 0, stream>>>(Wq, wq_bf);
  cvt_kernel<<<4096, 256, 0, stream>>>(Wk, wk_bf);
  cvt_kernel<<<4096, 256, 0, stream>>>(Wv, wv_bf);
  cvt_kernel<<<16384, 256, 0, stream>>>(Wo, wo_bf);

  gemm_bt<unsigned short><<<dim3(32, 32), 256, 0, stream>>>(hs_bf, wq_bf, q_ws, 4096, 4096, 4096);
  gemm_bt<unsigned short><<<dim3(32, 8), 256, 0, stream>>>(hs_bf, wk_bf, k_ws, 4096, 1024, 4096);
  gemm_bt<unsigned short><<<dim3(32, 8), 256, 0, stream>>>(hs_bf, wv_bf, v_ws, 4096, 1024, 4096);

  rope_repack<<<4096, 256, 0, stream>>>(q_ws, k_ws, cosT, sinT, q_r, k_r);
  transpose_v<<<512, 256, 0, stream>>>(v_ws, v_t);

  attn_kernel<<<dim3(32, 64), 256, 0, stream>>>(q_r, k_r, v_t, attnb);

  gemm_bt<float><<<dim3(32, 32), 256, 0, stream>>>(attnb, wo_bf, out, 4096, 4096, 4096);
}

// Round 3
// 992.463 us; speedup vs baseline: 1.0758x; 1.0758x over previous
//
#include <hip/hip_runtime.h>

// ---------------- types / helpers ----------------
typedef float f32x4 __attribute__((ext_vector_type(4)));
typedef __bf16 bf16x8 __attribute__((ext_vector_type(8)));
typedef __bf16 bf16x4 __attribute__((ext_vector_type(4)));
typedef unsigned short ushortx8 __attribute__((ext_vector_type(8)));

__device__ __forceinline__ unsigned short f2bf(float f) {
  unsigned int u = __builtin_bit_cast(unsigned int, f);
  u += 0x7fffu + ((u >> 16) & 1u);
  return (unsigned short)(u >> 16);
}
__device__ __forceinline__ float bf2f(unsigned short s) {
  return __builtin_bit_cast(float, ((unsigned int)s) << 16);
}

#define GLDS16(gp, lp)                                                         \
  __builtin_amdgcn_global_load_lds(                                            \
      (const __attribute__((address_space(1))) unsigned int*)(const void*)(gp),\
      (__attribute__((address_space(3))) unsigned int*)(void*)(lp), 16, 0, 0)

// ---------------- fp32 -> bf16 convert ----------------
__global__ void cvt_kernel(const float* __restrict__ in,
                           unsigned short* __restrict__ out) {
  int i = (blockIdx.x * 256 + threadIdx.x) * 4;
  float4 v = *reinterpret_cast<const float4*>(in + i);
  ushort4 o;
  o.x = f2bf(v.x); o.y = f2bf(v.y); o.z = f2bf(v.z); o.w = f2bf(v.w);
  *reinterpret_cast<ushort4*>(out + i) = o;
}

// ---------------- bf16 GEMM core (m97 structure) ----------------
// C[M][N] = A[M][K] * B[N][K]^T. 128x128 tile, BK=32, 4 waves.
template <typename OutT>
__device__ __forceinline__ void gemm_body(
    const unsigned short* __restrict__ Ap, const unsigned short* __restrict__ Bp,
    OutT* __restrict__ Cp, int N, int K, int bm, int bn,
    unsigned short* smem) {
  const int tid = threadIdx.x;
  const int wave = tid >> 6, lane = tid & 63;
  const int g = lane >> 4, l15 = lane & 15;
  const int wm = (wave >> 1) * 64, wn = (wave & 1) * 64;
  unsigned short* As = smem;
  unsigned short* Bs = smem + 128 * 32;
  f32x4 acc[4][4] = {};
  for (int k0 = 0; k0 < K; k0 += 32) {
    __syncthreads();
#pragma unroll
    for (int j = 0; j < 4; ++j) {
      int unit = wave * 256 + j * 64 + lane;
      const unsigned short* gp;
      if (unit < 512) {
        gp = Ap + (size_t)(bm + (unit >> 2)) * K + k0 + (unit & 3) * 8;
      } else {
        int bu = unit - 512;
        gp = Bp + (size_t)(bn + (bu >> 2)) * K + k0 + (bu & 3) * 8;
      }
      GLDS16(gp, (char*)smem + (wave * 256 + j * 64) * 16);
    }
    __syncthreads();
    bf16x8 a[4], b[4];
#pragma unroll
    for (int mi = 0; mi < 4; ++mi)
      a[mi] = *reinterpret_cast<const bf16x8*>(&As[(wm + mi * 16 + l15) * 32 + g * 8]);
#pragma unroll
    for (int nj = 0; nj < 4; ++nj)
      b[nj] = *reinterpret_cast<const bf16x8*>(&Bs[(wn + nj * 16 + l15) * 32 + g * 8]);
#pragma unroll
    for (int mi = 0; mi < 4; ++mi)
#pragma unroll
      for (int nj = 0; nj < 4; ++nj)
        acc[mi][nj] = __builtin_amdgcn_mfma_f32_16x16x32_bf16(a[mi], b[nj], acc[mi][nj], 0, 0, 0);
  }
#pragma unroll
  for (int mi = 0; mi < 4; ++mi)
#pragma unroll
    for (int nj = 0; nj < 4; ++nj) {
      int r0 = bm + wm + mi * 16 + g * 4;
      int c0 = bn + wn + nj * 16 + l15;
#pragma unroll
      for (int r = 0; r < 4; ++r) {
        float v = acc[mi][nj][r];
        if constexpr (sizeof(OutT) == 2)
          Cp[(size_t)(r0 + r) * N + c0] = (OutT)f2bf(v);
        else
          Cp[(size_t)(r0 + r) * N + c0] = (OutT)v;
      }
    }
}

__global__ __launch_bounds__(256, 2) void gemm_of(
    const unsigned short* __restrict__ Ap, const unsigned short* __restrict__ Bp,
    float* __restrict__ Cp, int M, int N, int K) {
  __shared__ __align__(16) unsigned short smem[2 * 128 * 32];
  gemm_body<float>(Ap, Bp, Cp, N, K, blockIdx.x * 128, blockIdx.y * 128, smem);
}

// fused QKV: y<32 -> Wq, y<40 -> Wk, else Wv. M=K=4096 throughout.
__global__ __launch_bounds__(256, 2) void gemm_qkv(
    const unsigned short* __restrict__ Ap, const unsigned short* __restrict__ Wq,
    const unsigned short* __restrict__ Wk, const unsigned short* __restrict__ Wv,
    unsigned short* __restrict__ q, unsigned short* __restrict__ k,
    unsigned short* __restrict__ v) {
  __shared__ __align__(16) unsigned short smem[2 * 128 * 32];
  int y = blockIdx.y;
  const unsigned short* Bp; unsigned short* Cp; int N, bn;
  if (y < 32)      { Bp = Wq; Cp = q; N = 4096; bn = y * 128; }
  else if (y < 40) { Bp = Wk; Cp = k; N = 1024; bn = (y - 32) * 128; }
  else             { Bp = Wv; Cp = v; N = 1024; bn = (y - 40) * 128; }
  gemm_body<unsigned short>(Ap, Bp, Cp, N, 4096, blockIdx.x * 128, bn, smem);
}

// ---------------- RoPE + repack ----------------
// Q gets scale/sqrt(d)*log2(e) folded in (exp2-domain softmax downstream).
__global__ void rope_repack(const unsigned short* __restrict__ qws,
                            const unsigned short* __restrict__ kws,
                            const float* __restrict__ cosT,
                            const float* __restrict__ sinT,
                            unsigned short* __restrict__ qr,
                            unsigned short* __restrict__ kr) {
  const int row = blockIdx.x;           // b*S + s
  const int b = row >> 11, s = row & 2047;
  const int t = threadIdx.x;
  const int h = t >> 3, d0 = (t & 7) * 8;
  const float* cr = cosT + s * 128;
  const float* sr = sinT + s * 128;
  float cl[8], chh[8], sl[8], shh[8];
#pragma unroll
  for (int i = 0; i < 8; ++i) {
    cl[i] = cr[d0 + i]; chh[i] = cr[64 + d0 + i];
    sl[i] = sr[d0 + i]; shh[i] = sr[64 + d0 + i];
  }
  constexpr float SCALE2 = 0.12751744726f;  // (1/sqrt(128)) * log2(e)
  {
    const unsigned short* px = &qws[(size_t)row * 4096 + h * 128 + d0];
    ushortx8 xl = *reinterpret_cast<const ushortx8*>(px);
    ushortx8 xh = *reinterpret_cast<const ushortx8*>(px + 64);
    ushortx8 ol, oh;
#pragma unroll
    for (int i = 0; i < 8; ++i) {
      float lo = bf2f(xl[i]), hi = bf2f(xh[i]);
      ol[i] = f2bf((lo * cl[i] - hi * sl[i]) * SCALE2);
      oh[i] = f2bf((hi * chh[i] + lo * shh[i]) * SCALE2);
    }
    unsigned short* po = &qr[((size_t)(b * 32 + h) * 2048 + s) * 128 + d0];
    *reinterpret_cast<ushortx8*>(po) = ol;
    *reinterpret_cast<ushortx8*>(po + 64) = oh;
  }
  if (t < 64) {
    const unsigned short* px = &kws[(size_t)row * 1024 + h * 128 + d0];
    ushortx8 xl = *reinterpret_cast<const ushortx8*>(px);
    ushortx8 xh = *reinterpret_cast<const ushortx8*>(px + 64);
    ushortx8 ol, oh;
#pragma unroll
    for (int i = 0; i < 8; ++i) {
      float lo = bf2f(xl[i]), hi = bf2f(xh[i]);
      ol[i] = f2bf(lo * cl[i] - hi * sl[i]);
      oh[i] = f2bf(hi * chh[i] + lo * shh[i]);
    }
    unsigned short* po = &kr[((size_t)(b * 8 + h) * 2048 + s) * 128 + d0];
    *reinterpret_cast<ushortx8*>(po) = ol;
    *reinterpret_cast<ushortx8*>(po + 64) = oh;
  }
}

// ---------------- V transpose ----------------
__global__ void transpose_v(const unsigned short* __restrict__ vws,
                            unsigned short* __restrict__ vt) {
  const int blk = blockIdx.x;
  const int s0 = (blk & 31) * 64;
  const int bh = blk >> 5;
  const int b = bh >> 3, h = bh & 7;
  const int t = threadIdx.x;
  __shared__ __align__(16) unsigned short tile[64][136];
#pragma unroll
  for (int p = 0; p < 4; ++p) {
    int u = p * 256 + t;
    int r = u >> 4, c = (u & 15) * 8;
    ushortx8 v = *reinterpret_cast<const ushortx8*>(
        &vws[(size_t)(b * 2048 + s0 + r) * 1024 + h * 128 + c]);
    *reinterpret_cast<ushortx8*>(&tile[r][c]) = v;
  }
  __syncthreads();
#pragma unroll
  for (int p = 0; p < 4; ++p) {
    int u = p * 256 + t;
    int d = u >> 3, sseg = (u & 7) * 8;
    ushortx8 w;
#pragma unroll
    for (int i = 0; i < 8; ++i) w[i] = tile[sseg + i][d];
    *reinterpret_cast<ushortx8*>(&vt[((size_t)bh * 128 + d) * 2048 + s0 + sseg]) = w;
  }
}

// ---------------- flash attention (causal, GQA 4:1), 8-wave paired tiles ---
// grid (16, B*32). Waves 0-3: q-tile i; waves 4-7: q-tile 31-i (balance).
// Both share K/V staging. T14 async-STAGE: load next tile to regs during
// compute, ds_write after barrier. exp2-domain softmax.
__global__ __launch_bounds__(512, 4) void attn_kernel(
    const unsigned short* __restrict__ qr, const unsigned short* __restrict__ kr,
    const unsigned short* __restrict__ vt, unsigned short* __restrict__ attn) {
  const int i = blockIdx.x;             // 0..15
  const int bh = blockIdx.y;            // 0..63
  const int b = bh >> 5, h = bh & 31, hkv = h >> 2;
  const int tid = threadIdx.x, wave = tid >> 6, lane = tid & 63;
  const int wgrp = wave >> 2, wsub = wave & 3;
  const int g = lane >> 4, l15 = lane & 15;
  const int qtile = (wgrp == 0) ? i : (31 - i);
  const int qs = qtile * 64;
  const int nt = 32 - i;                // kv tiles for the long group
  __shared__ __align__(16) unsigned short smem[25088];  // 50176 B
  unsigned short* Ks = smem;            // [64][128] swizzled, 8192 shorts
  unsigned short* Vs = smem + 8192;     // [128][64] swizzled, 8192 shorts
  unsigned short* pw = smem + 16384 + wave * 1088;  // per-wave P [16][68]
  const unsigned short* qbase = qr + (size_t)(b * 32 + h) * 2048 * 128;
  const unsigned short* kbase = kr + (size_t)(b * 8 + hkv) * 2048 * 128;
  const unsigned short* vbase = vt + (size_t)(b * 8 + hkv) * 128 * 2048;

  // fixed per-thread staging geometry (512 threads; 1024 16B-units each of K,V)
  const int kr0 = tid >> 4, kcby = (tid & 15) * 16;           // K rows tid>>4, +32
  const int vr0 = tid >> 3, vcby = (tid & 7) * 16;            // V rows tid>>3, +64
  const int dK0 = ((kr0 * 256 + kcby) ^ ((kr0 & 7) << 4));
  const int dV0 = ((vr0 * 128 + vcby) ^ ((vr0 & 7) << 4));

  // Q fragments in registers
  bf16x8 qf[4];
  const int qrow = qs + wsub * 16 + l15;
#pragma unroll
  for (int c = 0; c < 4; ++c)
    qf[c] = *reinterpret_cast<const bf16x8*>(&qbase[(size_t)qrow * 128 + c * 32 + g * 8]);

  f32x4 o[8] = {};
  float m_[4], l_[4];
#pragma unroll
  for (int r = 0; r < 4; ++r) { m_[r] = -1e30f; l_[r] = 0.f; }

  // prologue: stage tile 0
  {
    ushortx8 k0 = *reinterpret_cast<const ushortx8*>(&kbase[(size_t)kr0 * 128 + kcby / 2]);
    ushortx8 k1 = *reinterpret_cast<const ushortx8*>(&kbase[(size_t)(kr0 + 32) * 128 + kcby / 2]);
    ushortx8 v0 = *reinterpret_cast<const ushortx8*>(&vbase[(size_t)vr0 * 2048 + vcby / 2]);
    ushortx8 v1 = *reinterpret_cast<const ushortx8*>(&vbase[(size_t)(vr0 + 64) * 2048 + vcby / 2]);
    *reinterpret_cast<ushortx8*>((char*)Ks + dK0) = k0;
    *reinterpret_cast<ushortx8*>((char*)Ks + dK0 + 8192) = k1;
    *reinterpret_cast<ushortx8*>((char*)Vs + dV0) = v0;
    *reinterpret_cast<ushortx8*>((char*)Vs + dV0 + 8192) = v1;
  }
  __syncthreads();

  for (int t = 0; t < nt; ++t) {
    const int kv0 = t * 64;
    const bool have_next = (t + 1 < nt);
    ushortx8 k0n, k1n, v0n, v1n;
    if (have_next) {  // T14: issue next-tile loads early (hide under compute)
      const int kvn = kv0 + 64;
      k0n = *reinterpret_cast<const ushortx8*>(&kbase[(size_t)(kvn + kr0) * 128 + kcby / 2]);
      k1n = *reinterpret_cast<const ushortx8*>(&kbase[(size_t)(kvn + kr0 + 32) * 128 + kcby / 2]);
      v0n = *reinterpret_cast<const ushortx8*>(&vbase[(size_t)vr0 * 2048 + kvn + vcby / 2]);
      v1n = *reinterpret_cast<const ushortx8*>(&vbase[(size_t)(vr0 + 64) * 2048 + kvn + vcby / 2]);
    }
    if (t <= qtile) {
      // S = Q K^T (base-2 logits)
      f32x4 sc[4];
#pragma unroll
      for (int nb = 0; nb < 4; ++nb) {
        f32x4 a4 = {0.f, 0.f, 0.f, 0.f};
        const int n = nb * 16 + l15;
#pragma unroll
        for (int c = 0; c < 4; ++c) {
          int kby = (c * 32 + g * 8) * 2;
          bf16x8 kf = *reinterpret_cast<const bf16x8*>(
              (char*)Ks + ((n * 256 + kby) ^ ((n & 7) << 4)));
          a4 = __builtin_amdgcn_mfma_f32_16x16x32_bf16(qf[c], kf, a4, 0, 0, 0);
        }
        sc[nb] = a4;
      }
      if (t == qtile) {  // causal mask on diagonal tile
#pragma unroll
        for (int nb = 0; nb < 4; ++nb) {
          int kv = kv0 + nb * 16 + l15;
#pragma unroll
          for (int r = 0; r < 4; ++r)
            if (kv > qs + wsub * 16 + g * 4 + r) sc[nb][r] = -1e30f;
        }
      }
      // online softmax (exp2 domain)
      float sf[4];
#pragma unroll
      for (int r = 0; r < 4; ++r) {
        float tm = fmaxf(fmaxf(sc[0][r], sc[1][r]), fmaxf(sc[2][r], sc[3][r]));
#pragma unroll
        for (int off = 8; off; off >>= 1) tm = fmaxf(tm, __shfl_xor(tm, off, 16));
        float mn = fmaxf(m_[r], tm);
        sf[r] = exp2f(m_[r] - mn);
        m_[r] = mn;
      }
      float rs[4] = {0.f, 0.f, 0.f, 0.f};
#pragma unroll
      for (int nb = 0; nb < 4; ++nb)
#pragma unroll
        for (int r = 0; r < 4; ++r) {
          float p = exp2f(sc[nb][r] - m_[r]);
          sc[nb][r] = p;
          rs[r] += p;
        }
#pragma unroll
      for (int r = 0; r < 4; ++r) {
#pragma unroll
        for (int off = 8; off; off >>= 1) rs[r] += __shfl_xor(rs[r], off, 16);
        l_[r] = l_[r] * sf[r] + rs[r];
      }
#pragma unroll
      for (int db = 0; db < 8; ++db)
#pragma unroll
        for (int r = 0; r < 4; ++r) o[db][r] *= sf[r];
      // P -> wave-local LDS (stride 68: conflict-free u16 writes)
#pragma unroll
      for (int nb = 0; nb < 4; ++nb)
#pragma unroll
        for (int r = 0; r < 4; ++r)
          pw[(g * 4 + r) * 68 + nb * 16 + l15] = f2bf(sc[nb][r]);
      asm volatile("s_waitcnt lgkmcnt(0)" ::: "memory");
      __builtin_amdgcn_sched_barrier(0);
      // O += P V
#pragma unroll
      for (int c2 = 0; c2 < 2; ++c2) {
        const int pb = l15 * 68 + c2 * 32 + g * 8;
        bf16x4 plo = *reinterpret_cast<const bf16x4*>(&pw[pb]);
        bf16x4 phi = *reinterpret_cast<const bf16x4*>(&pw[pb + 4]);
        bf16x8 pf;
        pf[0] = plo[0]; pf[1] = plo[1]; pf[2] = plo[2]; pf[3] = plo[3];
        pf[4] = phi[0]; pf[5] = phi[1]; pf[6] = phi[2]; pf[7] = phi[3];
#pragma unroll
        for (int db = 0; db < 8; ++db) {
          int n = db * 16 + l15;
          int kby = (c2 * 32 + g * 8) * 2;
          bf16x8 vf = *reinterpret_cast<const bf16x8*>(
              (char*)Vs + ((n * 128 + kby) ^ ((n & 7) << 4)));
          o[db] = __builtin_amdgcn_mfma_f32_16x16x32_bf16(pf, vf, o[db], 0, 0, 0);
        }
      }
    }
    __syncthreads();            // all waves done reading Ks/Vs
    if (have_next) {
      *reinterpret_cast<ushortx8*>((char*)Ks + dK0) = k0n;
      *reinterpret_cast<ushortx8*>((char*)Ks + dK0 + 8192) = k1n;
      *reinterpret_cast<ushortx8*>((char*)Vs + dV0) = v0n;
      *reinterpret_cast<ushortx8*>((char*)Vs + dV0 + 8192) = v1n;
    }
    __syncthreads();            // staging visible
  }

  // epilogue: normalize, stage via LDS (stride 132), coalesced store
  float inv[4];
#pragma unroll
  for (int r = 0; r < 4; ++r) inv[r] = 1.f / l_[r];
  __syncthreads();
  unsigned short* ob = smem + wave * 2112;  // [16][132]
#pragma unroll
  for (int db = 0; db < 8; ++db)
#pragma unroll
    for (int r = 0; r < 4; ++r)
      ob[(g * 4 + r) * 132 + db * 16 + l15] = f2bf(o[db][r] * inv[r]);
  asm volatile("s_waitcnt lgkmcnt(0)" ::: "memory");
  __builtin_amdgcn_sched_barrier(0);
#pragma unroll
  for (int p = 0; p < 8; ++p) {
    int u = p * 64 + lane;
    int rr = u >> 5, sg = (u & 31) * 4;
    ushort4 w = *reinterpret_cast<const ushort4*>(&ob[rr * 132 + sg]);
    *reinterpret_cast<ushort4*>(
        &attn[(size_t)(b * 2048 + qs + wsub * 16 + rr) * 4096 + h * 128 + sg]) = w;
  }
}

// ---------------- host ----------------
extern "C" void kernel_launch(void* const* d_in, const int* in_sizes, int n_in,
                              void* d_out, int out_size, void* d_ws, size_t ws_size,
                              hipStream_t stream) {
  const float* hs   = (const float*)d_in[0];
  const float* Wq   = (const float*)d_in[1];
  const float* Wk   = (const float*)d_in[2];
  const float* Wv   = (const float*)d_in[3];
  const float* Wo   = (const float*)d_in[4];
  const float* cosT = (const float*)d_in[5];
  const float* sinT = (const float*)d_in[6];
  char* ws = (char*)d_ws;
  unsigned short* hs_bf = (unsigned short*)(ws + 0);          // later attn buffer
  unsigned short* wq_bf = (unsigned short*)(ws + 33554432);   // later q_r
  unsigned short* wk_bf = (unsigned short*)(ws + 67108864);   // later k_r
  unsigned short* wv_bf = (unsigned short*)(ws + 75497472);   // later v_t
  unsigned short* wo_bf = (unsigned short*)(ws + 83886080);
  unsigned short* q_ws  = (unsigned short*)(ws + 117440512);
  unsigned short* k_ws  = (unsigned short*)(ws + 150994944);
  unsigned short* v_ws  = (unsigned short*)(ws + 159383552);
  unsigned short* q_r   = wq_bf;
  unsigned short* k_r   = wk_bf;
  unsigned short* v_t   = wv_bf;
  unsigned short* attnb = hs_bf;
  float* out = (float*)d_out;

  cvt_kernel<<<16384, 256, 0, stream>>>(hs, hs_bf);
  cvt_kernel<<<16384, 256, 0, stream>>>(Wq, wq_bf);
  cvt_kernel<<<4096, 256, 0, stream>>>(Wk, wk_bf);
  cvt_kernel<<<4096, 256, 0, stream>>>(Wv, wv_bf);
  cvt_kernel<<<16384, 256, 0, stream>>>(Wo, wo_bf);

  gemm_qkv<<<dim3(32, 48), 256, 0, stream>>>(hs_bf, wq_bf, wk_bf, wv_bf,
                                             q_ws, k_ws, v_ws);

  rope_repack<<<4096, 256, 0, stream>>>(q_ws, k_ws, cosT, sinT, q_r, k_r);
  transpose_v<<<512, 256, 0, stream>>>(v_ws, v_t);

  attn_kernel<<<dim3(16, 64), 512, 0, stream>>>(q_r, k_r, v_t, attnb);

  gemm_of<<<dim3(32, 32), 256, 0, stream>>>(attnb, wo_bf, out, 4096, 4096, 4096);
}

// Round 4
// 773.506 us; speedup vs baseline: 1.3803x; 1.2831x over previous
//
#include <hip/hip_runtime.h>

// ---------------- types / helpers ----------------
typedef float f32x4 __attribute__((ext_vector_type(4)));
typedef float f32x16 __attribute__((ext_vector_type(16)));
typedef __bf16 bf16x8 __attribute__((ext_vector_type(8)));
typedef unsigned short ushortx8 __attribute__((ext_vector_type(8)));
typedef unsigned int uint32x4 __attribute__((ext_vector_type(4)));

__device__ __forceinline__ unsigned short f2bf(float f) {
  unsigned int u = __builtin_bit_cast(unsigned int, f);
  u += 0x7fffu + ((u >> 16) & 1u);
  return (unsigned short)(u >> 16);
}
__device__ __forceinline__ float bf2f(unsigned short s) {
  return __builtin_bit_cast(float, ((unsigned int)s) << 16);
}
// pack two f32 -> u32 of 2 bf16 (truncation; P in [0,256], rel err 2^-8 ok)
__device__ __forceinline__ unsigned pk2(float a, float b) {
  return (__builtin_bit_cast(unsigned, b) & 0xffff0000u) |
         (__builtin_bit_cast(unsigned, a) >> 16);
}

#define GLDS16(gp, lp)                                                         \
  __builtin_amdgcn_global_load_lds(                                            \
      (const __attribute__((address_space(1))) unsigned int*)(const void*)(gp),\
      (__attribute__((address_space(3))) unsigned int*)(void*)(lp), 16, 0, 0)

// ---------------- fp32 -> bf16 convert ----------------
__global__ void cvt_kernel(const float* __restrict__ in,
                           unsigned short* __restrict__ out) {
  int i = (blockIdx.x * 256 + threadIdx.x) * 4;
  float4 v = *reinterpret_cast<const float4*>(in + i);
  ushort4 o;
  o.x = f2bf(v.x); o.y = f2bf(v.y); o.z = f2bf(v.z); o.w = f2bf(v.w);
  *reinterpret_cast<ushort4*>(out + i) = o;
}

// ---------------- bf16 GEMM core (m97 structure) ----------------
template <typename OutT>
__device__ __forceinline__ void gemm_body(
    const unsigned short* __restrict__ Ap, const unsigned short* __restrict__ Bp,
    OutT* __restrict__ Cp, int N, int K, int bm, int bn,
    unsigned short* smem) {
  const int tid = threadIdx.x;
  const int wave = tid >> 6, lane = tid & 63;
  const int g = lane >> 4, l15 = lane & 15;
  const int wm = (wave >> 1) * 64, wn = (wave & 1) * 64;
  unsigned short* As = smem;
  unsigned short* Bs = smem + 128 * 32;
  f32x4 acc[4][4] = {};
  for (int k0 = 0; k0 < K; k0 += 32) {
    __syncthreads();
#pragma unroll
    for (int j = 0; j < 4; ++j) {
      int unit = wave * 256 + j * 64 + lane;
      const unsigned short* gp;
      if (unit < 512) {
        gp = Ap + (size_t)(bm + (unit >> 2)) * K + k0 + (unit & 3) * 8;
      } else {
        int bu = unit - 512;
        gp = Bp + (size_t)(bn + (bu >> 2)) * K + k0 + (bu & 3) * 8;
      }
      GLDS16(gp, (char*)smem + (wave * 256 + j * 64) * 16);
    }
    __syncthreads();
    bf16x8 a[4], b[4];
#pragma unroll
    for (int mi = 0; mi < 4; ++mi)
      a[mi] = *reinterpret_cast<const bf16x8*>(&As[(wm + mi * 16 + l15) * 32 + g * 8]);
#pragma unroll
    for (int nj = 0; nj < 4; ++nj)
      b[nj] = *reinterpret_cast<const bf16x8*>(&Bs[(wn + nj * 16 + l15) * 32 + g * 8]);
#pragma unroll
    for (int mi = 0; mi < 4; ++mi)
#pragma unroll
      for (int nj = 0; nj < 4; ++nj)
        acc[mi][nj] = __builtin_amdgcn_mfma_f32_16x16x32_bf16(a[mi], b[nj], acc[mi][nj], 0, 0, 0);
  }
#pragma unroll
  for (int mi = 0; mi < 4; ++mi)
#pragma unroll
    for (int nj = 0; nj < 4; ++nj) {
      int r0 = bm + wm + mi * 16 + g * 4;
      int c0 = bn + wn + nj * 16 + l15;
#pragma unroll
      for (int r = 0; r < 4; ++r) {
        float v = acc[mi][nj][r];
        if constexpr (sizeof(OutT) == 2)
          Cp[(size_t)(r0 + r) * N + c0] = (OutT)f2bf(v);
        else
          Cp[(size_t)(r0 + r) * N + c0] = (OutT)v;
      }
    }
}

__global__ __launch_bounds__(256, 2) void gemm_of(
    const unsigned short* __restrict__ Ap, const unsigned short* __restrict__ Bp,
    float* __restrict__ Cp, int M, int N, int K) {
  __shared__ __align__(16) unsigned short smem[2 * 128 * 32];
  gemm_body<float>(Ap, Bp, Cp, N, K, blockIdx.x * 128, blockIdx.y * 128, smem);
}

__global__ __launch_bounds__(256, 2) void gemm_qkv(
    const unsigned short* __restrict__ Ap, const unsigned short* __restrict__ Wq,
    const unsigned short* __restrict__ Wk, const unsigned short* __restrict__ Wv,
    unsigned short* __restrict__ q, unsigned short* __restrict__ k,
    unsigned short* __restrict__ v) {
  __shared__ __align__(16) unsigned short smem[2 * 128 * 32];
  int y = blockIdx.y;
  const unsigned short* Bp; unsigned short* Cp; int N, bn;
  if (y < 32)      { Bp = Wq; Cp = q; N = 4096; bn = y * 128; }
  else if (y < 40) { Bp = Wk; Cp = k; N = 1024; bn = (y - 32) * 128; }
  else             { Bp = Wv; Cp = v; N = 1024; bn = (y - 40) * 128; }
  gemm_body<unsigned short>(Ap, Bp, Cp, N, 4096, blockIdx.x * 128, bn, smem);
}

// ---------------- RoPE + repack (Q gets scale*log2e folded) ----------------
__global__ void rope_repack(const unsigned short* __restrict__ qws,
                            const unsigned short* __restrict__ kws,
                            const float* __restrict__ cosT,
                            const float* __restrict__ sinT,
                            unsigned short* __restrict__ qr,
                            unsigned short* __restrict__ kr) {
  const int row = blockIdx.x;           // b*S + s
  const int b = row >> 11, s = row & 2047;
  const int t = threadIdx.x;
  const int h = t >> 3, d0 = (t & 7) * 8;
  const float* cr = cosT + s * 128;
  const float* sr = sinT + s * 128;
  float cl[8], chh[8], sl[8], shh[8];
#pragma unroll
  for (int i = 0; i < 8; ++i) {
    cl[i] = cr[d0 + i]; chh[i] = cr[64 + d0 + i];
    sl[i] = sr[d0 + i]; shh[i] = sr[64 + d0 + i];
  }
  constexpr float SCALE2 = 0.12751744726f;  // (1/sqrt(128)) * log2(e)
  {
    const unsigned short* px = &qws[(size_t)row * 4096 + h * 128 + d0];
    ushortx8 xl = *reinterpret_cast<const ushortx8*>(px);
    ushortx8 xh = *reinterpret_cast<const ushortx8*>(px + 64);
    ushortx8 ol, oh;
#pragma unroll
    for (int i = 0; i < 8; ++i) {
      float lo = bf2f(xl[i]), hi = bf2f(xh[i]);
      ol[i] = f2bf((lo * cl[i] - hi * sl[i]) * SCALE2);
      oh[i] = f2bf((hi * chh[i] + lo * shh[i]) * SCALE2);
    }
    unsigned short* po = &qr[((size_t)(b * 32 + h) * 2048 + s) * 128 + d0];
    *reinterpret_cast<ushortx8*>(po) = ol;
    *reinterpret_cast<ushortx8*>(po + 64) = oh;
  }
  if (t < 64) {
    const unsigned short* px = &kws[(size_t)row * 1024 + h * 128 + d0];
    ushortx8 xl = *reinterpret_cast<const ushortx8*>(px);
    ushortx8 xh = *reinterpret_cast<const ushortx8*>(px + 64);
    ushortx8 ol, oh;
#pragma unroll
    for (int i = 0; i < 8; ++i) {
      float lo = bf2f(xl[i]), hi = bf2f(xh[i]);
      ol[i] = f2bf(lo * cl[i] - hi * sl[i]);
      oh[i] = f2bf(hi * chh[i] + lo * shh[i]);
    }
    unsigned short* po = &kr[((size_t)(b * 8 + h) * 2048 + s) * 128 + d0];
    *reinterpret_cast<ushortx8*>(po) = ol;
    *reinterpret_cast<ushortx8*>(po + 64) = oh;
  }
}

// ---------------- V transpose ----------------
__global__ void transpose_v(const unsigned short* __restrict__ vws,
                            unsigned short* __restrict__ vt) {
  const int blk = blockIdx.x;
  const int s0 = (blk & 31) * 64;
  const int bh = blk >> 5;
  const int b = bh >> 3, h = bh & 7;
  const int t = threadIdx.x;
  __shared__ __align__(16) unsigned short tile[64][136];
#pragma unroll
  for (int p = 0; p < 4; ++p) {
    int u = p * 256 + t;
    int r = u >> 4, c = (u & 15) * 8;
    ushortx8 v = *reinterpret_cast<const ushortx8*>(
        &vws[(size_t)(b * 2048 + s0 + r) * 1024 + h * 128 + c]);
    *reinterpret_cast<ushortx8*>(&tile[r][c]) = v;
  }
  __syncthreads();
#pragma unroll
  for (int p = 0; p < 4; ++p) {
    int u = p * 256 + t;
    int d = u >> 3, sseg = (u & 7) * 8;
    ushortx8 w;
#pragma unroll
    for (int i = 0; i < 8; ++i) w[i] = tile[sseg + i][d];
    *reinterpret_cast<ushortx8*>(&vt[((size_t)bh * 128 + d) * 2048 + s0 + sseg]) = w;
  }
}

// ---------------- flash attention: 8 waves x 32 q-rows, 32x32x16 swapped QK -
// grid (4, B*32). Block does q-range qp*256 (4qp+4 kv tiles) then the mirror
// range 2048-256(qp+1) (32-4qp tiles): 36 tiles/block everywhere (balanced).
// K/V double-buffered in LDS via global_load_lds with pre-swizzled source.
// S^T = mfma(K, Q): lane owns one q-row -> in-lane softmax, in-register P.
__global__ __launch_bounds__(512, 2) void attn_kernel(
    const unsigned short* __restrict__ qr, const unsigned short* __restrict__ kr,
    const unsigned short* __restrict__ vt, unsigned short* __restrict__ attn) {
  const int qp = blockIdx.x;            // 0..3
  const int bh = blockIdx.y;            // 0..63
  const int b = bh >> 5, h = bh & 31, hkv = h >> 2;
  const int tid = threadIdx.x, wave = tid >> 6, lane = tid & 63;
  const int hi = lane >> 5, l31 = lane & 31;
  __shared__ __align__(16) char smem[65536];  // K/V dbuf; aliased as O-stage
  const unsigned short* qbase = qr + (size_t)(b * 32 + h) * 2048 * 128;
  const unsigned short* kbase = kr + (size_t)(b * 8 + hkv) * 2048 * 128;
  const unsigned short* vbase = vt + (size_t)(b * 8 + hkv) * 128 * 2048;

  // staging geometry: K tile 64x128 (1024 16B units), V^T tile 128x64 (1024)
  const int ku1 = tid, ku2 = tid + 512;
  const int kvr1 = ku1 >> 4, kc1 = ku1 & 15;
  const int kvr2 = ku2 >> 4, kc2 = ku2 & 15;
  const int dvr1 = ku1 >> 3, vc1 = ku1 & 7;
  const int dvr2 = ku2 >> 3, vc2 = ku2 & 7;

#define STAGE(tile, bsel)                                                      \
  {                                                                            \
    const int kv0s = (tile) * 64;                                              \
    char* Kd = smem + (bsel) * 32768;                                          \
    char* Vd = Kd + 16384;                                                     \
    GLDS16(kbase + (size_t)(kv0s + kvr1) * 128 + (kc1 ^ (kvr1 & 7)) * 8,       \
           Kd + ku1 * 16);                                                     \
    GLDS16(kbase + (size_t)(kv0s + kvr2) * 128 + (kc2 ^ (kvr2 & 7)) * 8,       \
           Kd + ku2 * 16);                                                     \
    GLDS16(vbase + (size_t)dvr1 * 2048 + kv0s + (vc1 ^ (dvr1 & 7)) * 8,        \
           Vd + ku1 * 16);                                                     \
    GLDS16(vbase + (size_t)dvr2 * 2048 + kv0s + (vc2 ^ (dvr2 & 7)) * 8,        \
           Vd + ku2 * 16);                                                     \
  }

#pragma unroll 1
  for (int phase = 0; phase < 2; ++phase) {
    const int q0 = (phase == 0) ? qp * 256 : 2048 - 256 * (qp + 1);
    const int NT = (phase == 0) ? 4 * qp + 4 : 32 - 4 * qp;
    const int qw0 = q0 + wave * 32;
    const int qg = qw0 + l31;           // this lane's q row
    // Q fragments: lane holds Q[qg][c*16 + hi*8 .. +7]
    bf16x8 qf[8];
#pragma unroll
    for (int c = 0; c < 8; ++c)
      qf[c] = *reinterpret_cast<const bf16x8*>(
          &qbase[(size_t)qg * 128 + c * 16 + hi * 8]);
    f32x16 o[4] = {};
    float m_ = -1e30f, l_ = 0.f;

    STAGE(0, 0);
    __syncthreads();

    for (int t = 0; t < NT; ++t) {
      const int cur = t & 1;
      if (t + 1 < NT) STAGE(t + 1, (t + 1) & 1);
      const int kv0 = t * 64;
      if (kv0 <= qw0 + 31) {            // wave has unmasked work
        const char* Kb = smem + cur * 32768;
        const char* Vb = Kb + 16384;
        // S^T = K * Q^T (2 kv-blocks of 32) over 8 d-chunks
        f32x16 s0 = {}, s1 = {};
#pragma unroll
        for (int c = 0; c < 8; ++c) {
          int r0 = l31;
          bf16x8 kf0 = *reinterpret_cast<const bf16x8*>(
              Kb + ((r0 * 256 + c * 32 + hi * 16) ^ ((r0 & 7) << 4)));
          s0 = __builtin_amdgcn_mfma_f32_32x32x16_bf16(kf0, qf[c], s0, 0, 0, 0);
          int r1 = 32 + l31;
          bf16x8 kf1 = *reinterpret_cast<const bf16x8*>(
              Kb + ((r1 * 256 + c * 32 + hi * 16) ^ ((r1 & 7) << 4)));
          s1 = __builtin_amdgcn_mfma_f32_32x32x16_bf16(kf1, qf[c], s1, 0, 0, 0);
        }
        // causal mask (diagonal band only)
        if (kv0 + 63 > qw0) {
#pragma unroll
          for (int rg = 0; rg < 16; ++rg) {
            int kvg = kv0 + (rg & 3) + 8 * (rg >> 2) + 4 * hi;
            if (kvg > qg) s0[rg] = -1e30f;
            if (kvg + 32 > qg) s1[rg] = -1e30f;
          }
        }
        // in-lane row max (q = l31), partner exchange across hi
        float tm = fmaxf(s0[0], s1[0]);
#pragma unroll
        for (int rg = 1; rg < 16; ++rg)
          tm = fmaxf(tm, fmaxf(s0[rg], s1[rg]));
        tm = fmaxf(tm, __shfl_xor(tm, 32));
        if (__any(tm > m_ + 8.0f)) {    // T13 defer-max: rare rescale
          float mn = fmaxf(m_, tm);
          float sf = exp2f(m_ - mn);
          l_ *= sf; m_ = mn;
#pragma unroll
          for (int rg = 0; rg < 16; ++rg) {
            float sq = __shfl(sf, (rg & 3) + 8 * (rg >> 2) + 4 * hi);
            o[0][rg] *= sq; o[1][rg] *= sq; o[2][rg] *= sq; o[3][rg] *= sq;
          }
        }
        // P = exp2(S - m), row-sum accumulate (own kv-half partial)
        float rs = 0.f;
#pragma unroll
        for (int rg = 0; rg < 16; ++rg) {
          s0[rg] = exp2f(s0[rg] - m_); rs += s0[rg];
          s1[rg] = exp2f(s1[rg] - m_); rs += s1[rg];
        }
        l_ += rs;
        // pack P -> bf16 pairs, exchange with hi-partner, build PV A-frags
        unsigned A0 = pk2(s0[0], s0[1]),  C0 = pk2(s0[2], s0[3]);
        unsigned B0 = pk2(s0[4], s0[5]),  D0 = pk2(s0[6], s0[7]);
        unsigned E0 = pk2(s0[8], s0[9]),  G0 = pk2(s0[10], s0[11]);
        unsigned F0 = pk2(s0[12], s0[13]), H0 = pk2(s0[14], s0[15]);
        unsigned A1 = pk2(s1[0], s1[1]),  C1 = pk2(s1[2], s1[3]);
        unsigned B1 = pk2(s1[4], s1[5]),  D1 = pk2(s1[6], s1[7]);
        unsigned E1 = pk2(s1[8], s1[9]),  G1 = pk2(s1[10], s1[11]);
        unsigned F1 = pk2(s1[12], s1[13]), H1 = pk2(s1[14], s1[15]);
        unsigned Ax = __shfl_xor(A0, 32), Bx = __shfl_xor(B0, 32);
        unsigned Cx = __shfl_xor(C0, 32), Dx = __shfl_xor(D0, 32);
        unsigned Ex = __shfl_xor(E0, 32), Fx = __shfl_xor(F0, 32);
        unsigned Gx = __shfl_xor(G0, 32), Hx = __shfl_xor(H0, 32);
        unsigned Ax1 = __shfl_xor(A1, 32), Bx1 = __shfl_xor(B1, 32);
        unsigned Cx1 = __shfl_xor(C1, 32), Dx1 = __shfl_xor(D1, 32);
        unsigned Ex1 = __shfl_xor(E1, 32), Fx1 = __shfl_xor(F1, 32);
        unsigned Gx1 = __shfl_xor(G1, 32), Hx1 = __shfl_xor(H1, 32);
        const bool hh = (hi != 0);
        uint32x4 w0, w1, w2, w3;
        w0[0] = hh ? Bx : A0;  w0[1] = hh ? Dx : C0;
        w0[2] = hh ? B0 : Ax;  w0[3] = hh ? D0 : Cx;
        w1[0] = hh ? Fx : E0;  w1[1] = hh ? Hx : G0;
        w1[2] = hh ? F0 : Ex;  w1[3] = hh ? H0 : Gx;
        w2[0] = hh ? Bx1 : A1; w2[1] = hh ? Dx1 : C1;
        w2[2] = hh ? B1 : Ax1; w2[3] = hh ? D1 : Cx1;
        w3[0] = hh ? Fx1 : E1; w3[1] = hh ? Hx1 : G1;
        w3[2] = hh ? F1 : Ex1; w3[3] = hh ? H1 : Gx1;
        bf16x8 pa[4];
        pa[0] = __builtin_bit_cast(bf16x8, w0);
        pa[1] = __builtin_bit_cast(bf16x8, w1);
        pa[2] = __builtin_bit_cast(bf16x8, w2);
        pa[3] = __builtin_bit_cast(bf16x8, w3);
        // O += P V  (4 kv-chunks x 4 dv-blocks)
#pragma unroll
        for (int dvb = 0; dvb < 4; ++dvb) {
          int rv = dvb * 32 + l31;
          int sw = (rv & 7) << 4;
#pragma unroll
          for (int kc = 0; kc < 4; ++kc) {
            bf16x8 vf = *reinterpret_cast<const bf16x8*>(
                Vb + ((rv * 128 + kc * 32 + hi * 16) ^ sw));
            o[dvb] = __builtin_amdgcn_mfma_f32_32x32x16_bf16(pa[kc], vf, o[dvb], 0, 0, 0);
          }
        }
      }
      __syncthreads();                  // drains vmcnt: next tile staged+visible
    }

    // ---- phase epilogue: normalize, stage O in LDS (aliases K/V), store ----
    float lt = l_ + __shfl_xor(l_, 32);
    float invl = 1.0f / lt;             // valid for q = l31 in all lanes
    float inq[16];
#pragma unroll
    for (int rg = 0; rg < 16; ++rg)
      inq[rg] = __shfl(invl, (rg & 3) + 8 * (rg >> 2) + 4 * hi);
    unsigned short* Ost = (unsigned short*)smem;  // [256][128]
#pragma unroll
    for (int dvb = 0; dvb < 4; ++dvb)
#pragma unroll
      for (int rg = 0; rg < 16; ++rg) {
        int row = wave * 32 + (rg & 3) + 8 * (rg >> 2) + 4 * hi;
        Ost[row * 128 + dvb * 32 + l31] = f2bf(o[dvb][rg] * inq[rg]);
      }
    __syncthreads();
#pragma unroll
    for (int p = 0; p < 8; ++p) {
      int u = p * 512 + tid;
      int row = u >> 4, seg = (u & 15) * 8;
      ushortx8 w = *reinterpret_cast<const ushortx8*>(&Ost[row * 128 + seg]);
      *reinterpret_cast<ushortx8*>(
          &attn[(size_t)(b * 2048 + q0 + row) * 4096 + h * 128 + seg]) = w;
    }
    __syncthreads();                    // before next phase staging overwrites
  }
#undef STAGE
}

// ---------------- host ----------------
extern "C" void kernel_launch(void* const* d_in, const int* in_sizes, int n_in,
                              void* d_out, int out_size, void* d_ws, size_t ws_size,
                              hipStream_t stream) {
  const float* hs   = (const float*)d_in[0];
  const float* Wq   = (const float*)d_in[1];
  const float* Wk   = (const float*)d_in[2];
  const float* Wv   = (const float*)d_in[3];
  const float* Wo   = (const float*)d_in[4];
  const float* cosT = (const float*)d_in[5];
  const float* sinT = (const float*)d_in[6];
  char* ws = (char*)d_ws;
  unsigned short* hs_bf = (unsigned short*)(ws + 0);          // later attn buffer
  unsigned short* wq_bf = (unsigned short*)(ws + 33554432);   // later q_r
  unsigned short* wk_bf = (unsigned short*)(ws + 67108864);   // later k_r
  unsigned short* wv_bf = (unsigned short*)(ws + 75497472);   // later v_t
  unsigned short* wo_bf = (unsigned short*)(ws + 83886080);
  unsigned short* q_ws  = (unsigned short*)(ws + 117440512);
  unsigned short* k_ws  = (unsigned short*)(ws + 150994944);
  unsigned short* v_ws  = (unsigned short*)(ws + 159383552);
  unsigned short* q_r   = wq_bf;
  unsigned short* k_r   = wk_bf;
  unsigned short* v_t   = wv_bf;
  unsigned short* attnb = hs_bf;
  float* out = (float*)d_out;

  cvt_kernel<<<16384, 256, 0, stream>>>(hs, hs_bf);
  cvt_kernel<<<16384, 256, 0, stream>>>(Wq, wq_bf);
  cvt_kernel<<<4096, 256, 0, stream>>>(Wk, wk_bf);
  cvt_kernel<<<4096, 256, 0, stream>>>(Wv, wv_bf);
  cvt_kernel<<<16384, 256, 0, stream>>>(Wo, wo_bf);

  gemm_qkv<<<dim3(32, 48), 256, 0, stream>>>(hs_bf, wq_bf, wk_bf, wv_bf,
                                             q_ws, k_ws, v_ws);

  rope_repack<<<4096, 256, 0, stream>>>(q_ws, k_ws, cosT, sinT, q_r, k_r);
  transpose_v<<<512, 256, 0, stream>>>(v_ws, v_t);

  attn_kernel<<<dim3(4, 64), 512, 0, stream>>>(q_r, k_r, v_t, attnb);

  gemm_of<<<dim3(32, 32), 256, 0, stream>>>(attnb, wo_bf, out, 4096, 4096, 4096);
}